// Round 12
// baseline (292.402 us; speedup 1.0000x reference)
//
#include <hip/hip_runtime.h>
#include <hip/hip_cooperative_groups.h>
#include <math.h>

namespace cg = cooperative_groups;

namespace {
constexpr int B = 4, R = 10, N = 64, E = 64, D = 300, H = 512;
constexpr int BR = B * R;        // 40
constexpr int NE = N * E;        // 4096
constexpr int S = BR * NE;       // 163840
constexpr float SLOPE = 0.2f;

// ws layout (floats)
constexpr int OFF_V1  = 0;                 // 300   Wn @ a1
constexpr int OFF_V2  = OFF_V1 + 300;      // 300   Wn @ a2
constexpr int OFF_U1  = OFF_V2 + 300;      // 512   Wq @ a1
constexpr int OFF_U2  = OFF_U1 + H;        // 512   Wq @ a2
constexpr int OFF_QP  = OFF_U2 + H;        // 40*512 q_proj
constexpr int OFF_QA1 = OFF_QP + BR * H;   // 40
constexpr int OFF_QA2 = OFF_QA1 + BR;      // 40
constexpr int OFF_S1  = OFF_QA2 + BR;      // 2560  scores1 (incl. qa1)
constexpr int OFF_RAW = OFF_S1 + BR * N;   // 163840 raw adj.v2 dots
constexpr int OFF_SC  = OFF_RAW + S;       // 163840 attn
constexpr int OFF_WO  = OFF_SC + S;        // 1310720 w_original
}

__device__ inline float waveReduce(float v) {
#pragma unroll
  for (int o = 32; o > 0; o >>= 1) v += __shfl_xor(v, o, 64);
  return v;
}

__device__ inline float dot4(float4 a, float4 b) {
  return a.x * b.x + a.y * b.y + a.z * b.z + a.w * b.w;
}

// One cooperative kernel, 4 phases. 512 thr/block, <=64 VGPR (launch_bounds),
// 30720 B LDS -> 4 blocks/CU co-resident guaranteed.
__global__ __launch_bounds__(512, 8) void k_mega(const float* __restrict__ adj,
                                                 const float* __restrict__ orig,
                                                 const float* __restrict__ ques,
                                                 const float* __restrict__ W,
                                                 const float* __restrict__ a,
                                                 float* __restrict__ out,
                                                 float* __restrict__ ws) {
  cg::grid_group grid = cg::this_grid();
  __shared__ __align__(16) float smem[7680];   // 30720 B
  const int tid  = threadIdx.x;
  const int lane = tid & 63, wave = tid >> 6;
  const int nblk = gridDim.x;
  const int gw0  = blockIdx.x * 8 + wave;   // global wave id
  const int gwN  = nblk * 8;

  // ---------- phase 0: vecs (W rows . a1/a2) ----------
  {
    const float4* a1f = reinterpret_cast<const float4*>(a);
    const float4* a2f = reinterpret_cast<const float4*>(a + H);
    float4 p0 = a1f[lane], p1 = a1f[64 + lane];
    float4 q0 = a2f[lane], q1 = a2f[64 + lane];
    for (int row = gw0; row < D + H; row += gwN) {
      const float4* rf = reinterpret_cast<const float4*>(W + (size_t)row * H);
      float4 x0 = rf[lane], x1 = rf[64 + lane];
      float s1 = dot4(x0, p0) + dot4(x1, p1);
      float s2 = dot4(x0, q0) + dot4(x1, q1);
      s1 = waveReduce(s1);
      s2 = waveReduce(s2);
      if (lane == 0) {
        if (row < D) { ws[OFF_V1 + row] = s1; ws[OFF_V2 + row] = s2; }
        else         { ws[OFF_U1 + row - D] = s1; ws[OFF_U2 + row - D] = s2; }
      }
    }
  }
  grid.sync();

  // ---------- phase 1: qproj+scores1 (40 blocks) overlapped with scores2 ----------
  for (int br = blockIdx.x; br < BR; br += nblk) {
    float* qs   = smem;        // 512
    float* red  = smem + 512;  // 16
    float* qa1p = smem + 528;
    qs[tid] = ques[(size_t)br * H + tid];
    __syncthreads();
    float acc = 0.f;
#pragma unroll 8
    for (int q = 0; q < H; ++q) acc = fmaf(qs[q], W[(size_t)(D + q) * H + tid], acc);
    ws[OFF_QP + br * H + tid] = acc;
    float p1 = qs[tid] * ws[OFF_U1 + tid];
    float p2 = qs[tid] * ws[OFF_U2 + tid];
    p1 = waveReduce(p1);
    p2 = waveReduce(p2);
    if (lane == 0) { red[wave] = p1; red[8 + wave] = p2; }
    __syncthreads();
    if (tid == 0) {
      float t1 = 0.f, t2 = 0.f;
#pragma unroll
      for (int i = 0; i < 8; ++i) { t1 += red[i]; t2 += red[8 + i]; }
      ws[OFF_QA1 + br] = t1;
      ws[OFF_QA2 + br] = t2;
      *qa1p = t1;
    }
    __syncthreads();
    float qa1 = *qa1p;
    const float4* vf = reinterpret_cast<const float4*>(ws + OFF_V1);
    float4 va = vf[lane];
    float4 vb = (lane < 11) ? vf[64 + lane] : make_float4(0.f, 0.f, 0.f, 0.f);
    for (int n = wave; n < N; n += 8) {
      const float4* rf = reinterpret_cast<const float4*>(orig + ((size_t)br * N + n) * D);
      float a0 = dot4(rf[lane], va);
      if (lane < 11) a0 += dot4(rf[64 + lane], vb);
      a0 = waveReduce(a0);
      if (lane == 0) ws[OFF_S1 + br * N + n] = a0 + qa1;
    }
    __syncthreads();
  }
  // scores2: grid-strided over all waves; 4 rows per group, 8 loads in flight.
  {
    const float4* vf = reinterpret_cast<const float4*>(ws + OFF_V2);
    float4 va = vf[lane];
    float4 vb = (lane < 11) ? vf[64 + lane] : make_float4(0.f, 0.f, 0.f, 0.f);
    for (int g = gw0; g < S / 4; g += gwN) {
      size_t r0 = (size_t)g * 4;
      const float4* P0 = reinterpret_cast<const float4*>(adj + (r0 + 0) * D);
      const float4* P1 = reinterpret_cast<const float4*>(adj + (r0 + 1) * D);
      const float4* P2 = reinterpret_cast<const float4*>(adj + (r0 + 2) * D);
      const float4* P3 = reinterpret_cast<const float4*>(adj + (r0 + 3) * D);
      float4 x0 = P0[lane], x1 = P1[lane], x2 = P2[lane], x3 = P3[lane];
      float a0 = dot4(x0, va), a1 = dot4(x1, va), a2 = dot4(x2, va), a3 = dot4(x3, va);
      if (lane < 11) {
        float4 y0 = P0[64 + lane], y1 = P1[64 + lane];
        float4 y2 = P2[64 + lane], y3 = P3[64 + lane];
        a0 += dot4(y0, vb); a1 += dot4(y1, vb);
        a2 += dot4(y2, vb); a3 += dot4(y3, vb);
      }
#pragma unroll
      for (int o = 32; o > 0; o >>= 1) {
        a0 += __shfl_xor(a0, o, 64);
        a1 += __shfl_xor(a1, o, 64);
        a2 += __shfl_xor(a2, o, 64);
        a3 += __shfl_xor(a3, o, 64);
      }
      float v = (lane == 0) ? a0 : (lane == 1) ? a1 : (lane == 2) ? a2 : a3;
      if (lane < 4) ws[OFF_RAW + r0 + lane] = v;
    }
  }
  grid.sync();

  // ---------- phase 2: softmax (jobs 0..31) + wo GEMM (jobs 32..351) ----------
  for (int vb = blockIdx.x; vb < 352; vb += nblk) {
    if (vb < 32) {
      int t = vb * 512 + tid;      // 0..16383 = B*N*E
      int b = t >> 12;
      int ne = t & 4095;
      int n = ne >> 6;
      const float* raw = ws + OFF_RAW;
      float v[R];
      float m = -1e30f;
#pragma unroll
      for (int r = 0; r < R; ++r) {
        int br = b * R + r;
        float sc = raw[(size_t)br * NE + ne] + ws[OFF_QA2 + br] + ws[OFF_S1 + br * N + n];
        sc = sc > 0.f ? sc : SLOPE * sc;
        v[r] = sc;
        m = fmaxf(m, sc);
      }
      float s = 0.f;
#pragma unroll
      for (int r = 0; r < R; ++r) { v[r] = __expf(v[r] - m); s += v[r]; }
      float inv = 1.f / s;
#pragma unroll
      for (int r = 0; r < R; ++r)
        ws[OFF_SC + (size_t)(b * R + r) * NE + ne] = v[r] * inv;
    } else {
      int bi = vb - 32;            // 0..319
      int br = bi >> 3, h0 = (bi & 7) * 64;
      float* sA = smem;            // 64x60
      float* sB = smem + 3840;     // 60x64
      const float4* sBf = reinterpret_cast<const float4*>(sB);
      int th = tid & 15, tn = tid >> 4;   // tn 0..31
      float ac[2][4] = {};
      for (int k0 = 0; k0 < D; k0 += 60) {
        __syncthreads();
        for (int idx = tid; idx < 3840; idx += 512) {
          int n = idx / 60, kk = idx % 60;
          sA[idx] = orig[((size_t)br * N + n) * D + k0 + kk];
        }
        for (int idx = tid; idx < 3840; idx += 512) {
          int kk = idx >> 6, hh = idx & 63;
          sB[idx] = W[(size_t)(k0 + kk) * H + h0 + hh];
        }
        __syncthreads();
#pragma unroll 4
        for (int kk = 0; kk < 60; ++kk) {
          float av0 = sA[(tn * 2 + 0) * 60 + kk];
          float av1 = sA[(tn * 2 + 1) * 60 + kk];
          float4 bv = sBf[kk * 16 + th];
          ac[0][0] = fmaf(av0, bv.x, ac[0][0]);
          ac[0][1] = fmaf(av0, bv.y, ac[0][1]);
          ac[0][2] = fmaf(av0, bv.z, ac[0][2]);
          ac[0][3] = fmaf(av0, bv.w, ac[0][3]);
          ac[1][0] = fmaf(av1, bv.x, ac[1][0]);
          ac[1][1] = fmaf(av1, bv.y, ac[1][1]);
          ac[1][2] = fmaf(av1, bv.z, ac[1][2]);
          ac[1][3] = fmaf(av1, bv.w, ac[1][3]);
        }
      }
#pragma unroll
      for (int i = 0; i < 2; ++i) {
        int n = tn * 2 + i;
#pragma unroll
        for (int j = 0; j < 4; ++j) {
          int h = h0 + th * 4 + j;
          ws[OFF_WO + ((size_t)br * N + n) * H + h] = ac[i][j] + ws[OFF_QP + br * H + h];
        }
      }
      __syncthreads();
    }
  }
  grid.sync();

  // ---------- phase 3: hprime = attn @ w_original, ELU ----------
  for (int vb = blockIdx.x; vb < 160; vb += nblk) {
    int br = vb >> 2, hc = vb & 3;
    int h = hc * 128 + (tid & 127);
    int ig = tid >> 7;               // 0..3 -> rows ig*16..ig*16+15
    float* sAtt = smem;              // 4096 floats
    __syncthreads();
    const float* att = ws + OFF_SC + (size_t)br * NE;
    for (int idx = tid; idx < 4096; idx += 512) sAtt[idx] = att[idx];
    __syncthreads();
    float acc[16] = {};
    const float* wo = ws + OFF_WO + (size_t)br * N * H;
    const float4* sAttf = reinterpret_cast<const float4*>(sAtt);
#pragma unroll 2
    for (int j4 = 0; j4 < 16; ++j4) {
      float w0 = wo[(size_t)(4 * j4 + 0) * H + h];
      float w1 = wo[(size_t)(4 * j4 + 1) * H + h];
      float w2 = wo[(size_t)(4 * j4 + 2) * H + h];
      float w3 = wo[(size_t)(4 * j4 + 3) * H + h];
#pragma unroll
      for (int ii = 0; ii < 16; ++ii) {
        float4 a4 = sAttf[(ig * 16 + ii) * 16 + j4];
        acc[ii] = fmaf(a4.x, w0, fmaf(a4.y, w1, fmaf(a4.z, w2, fmaf(a4.w, w3, acc[ii]))));
      }
    }
#pragma unroll
    for (int ii = 0; ii < 16; ++ii) {
      int i = ig * 16 + ii;
      float x = acc[ii];
      out[((size_t)br * N + i) * H + h] = x > 0.f ? x : expm1f(x);
    }
  }
}

extern "C" void kernel_launch(void* const* d_in, const int* in_sizes, int n_in,
                              void* d_out, int out_size, void* d_ws, size_t ws_size,
                              hipStream_t stream) {
  const float* adj  = (const float*)d_in[0];
  const float* orig = (const float*)d_in[1];
  const float* ques = (const float*)d_in[2];
  const float* W    = (const float*)d_in[3];
  const float* a    = (const float*)d_in[4];
  float* out = (float*)d_out;
  float* ws  = (float*)d_ws;

  int maxb = 0;
  (void)hipOccupancyMaxActiveBlocksPerMultiprocessor(&maxb, (const void*)k_mega, 512, 0);
  if (maxb < 1) maxb = 1;
  int grid = maxb * 256;
  if (grid > 1024) grid = 1024;

  void* args[] = {(void*)&adj, (void*)&orig, (void*)&ques, (void*)&W,
                  (void*)&a, (void*)&out, (void*)&ws};
  (void)hipLaunchCooperativeKernel((const void*)k_mega, dim3(grid), dim3(512),
                                   args, 0, stream);
}

// Round 13
// 229.744 us; speedup vs baseline: 1.2727x; 1.2727x over previous
//
#include <hip/hip_runtime.h>
#include <hip/hip_cooperative_groups.h>
#include <math.h>

namespace cg = cooperative_groups;

namespace {
constexpr int B = 4, R = 10, N = 64, E = 64, D = 300, H = 512;
constexpr int BR = B * R;        // 40
constexpr int NE = N * E;        // 4096
constexpr int S = BR * NE;       // 163840
constexpr float SLOPE = 0.2f;

// ws layout (floats)
constexpr int OFF_V1  = 0;                 // 300   Wn @ a1
constexpr int OFF_V2  = OFF_V1 + 300;      // 300   Wn @ a2
constexpr int OFF_U1  = OFF_V2 + 300;      // 512   Wq @ a1
constexpr int OFF_U2  = OFF_U1 + H;        // 512   Wq @ a2
constexpr int OFF_QP  = OFF_U2 + H;        // 40*512 q_proj
constexpr int OFF_QA1 = OFF_QP + BR * H;   // 40
constexpr int OFF_QA2 = OFF_QA1 + BR;      // 40
constexpr int OFF_S1  = OFF_QA2 + BR;      // 2560  scores1 (incl. qa1)
constexpr int OFF_RAW = OFF_S1 + BR * N;   // 163840 raw adj.v2 dots
constexpr int OFF_SC  = OFF_RAW + S;       // 163840 attn
constexpr int OFF_WO  = OFF_SC + S;        // 1310720 w_original
}

__device__ inline float waveReduce(float v) {
#pragma unroll
  for (int o = 32; o > 0; o >>= 1) v += __shfl_xor(v, o, 64);
  return v;
}

__device__ inline float dot4(float4 a, float4 b) {
  return a.x * b.x + a.y * b.y + a.z * b.z + a.w * b.w;
}

// One cooperative kernel, 4 phases. 512 thr/block.
// launch_bounds(512,4): VGPR cap 128 (not 64!) -> scores2 keeps 8 float4
// loads in flight; 2 blocks/CU via LDS+waves. R12's (512,8) squeezed VGPR
// to 28 and serialized all loads (286 GB/s).
__global__ __launch_bounds__(512, 4) void k_mega(const float* __restrict__ adj,
                                                 const float* __restrict__ orig,
                                                 const float* __restrict__ ques,
                                                 const float* __restrict__ W,
                                                 const float* __restrict__ a,
                                                 float* __restrict__ out,
                                                 float* __restrict__ ws) {
  cg::grid_group grid = cg::this_grid();
  __shared__ __align__(16) float smem[7680];   // 30720 B
  const int tid  = threadIdx.x;
  const int lane = tid & 63, wave = tid >> 6;
  const int nblk = gridDim.x;
  const int gw0  = blockIdx.x * 8 + wave;   // global wave id
  const int gwN  = nblk * 8;

  // ---------- phase 0: vecs (W rows . a1/a2) ----------
  {
    const float4* a1f = reinterpret_cast<const float4*>(a);
    const float4* a2f = reinterpret_cast<const float4*>(a + H);
    float4 p0 = a1f[lane], p1 = a1f[64 + lane];
    float4 q0 = a2f[lane], q1 = a2f[64 + lane];
    for (int row = gw0; row < D + H; row += gwN) {
      const float4* rf = reinterpret_cast<const float4*>(W + (size_t)row * H);
      float4 x0 = rf[lane], x1 = rf[64 + lane];
      float s1 = dot4(x0, p0) + dot4(x1, p1);
      float s2 = dot4(x0, q0) + dot4(x1, q1);
      s1 = waveReduce(s1);
      s2 = waveReduce(s2);
      if (lane == 0) {
        if (row < D) { ws[OFF_V1 + row] = s1; ws[OFF_V2 + row] = s2; }
        else         { ws[OFF_U1 + row - D] = s1; ws[OFF_U2 + row - D] = s2; }
      }
    }
  }
  grid.sync();

  // ---------- phase 1: qproj+scores1 (40 blocks) overlapped with scores2 ----------
  for (int br = blockIdx.x; br < BR; br += nblk) {
    float* qs   = smem;        // 512
    float* red  = smem + 512;  // 16
    float* qa1p = smem + 528;
    qs[tid] = ques[(size_t)br * H + tid];
    __syncthreads();
    float acc = 0.f;
#pragma unroll 8
    for (int q = 0; q < H; ++q) acc = fmaf(qs[q], W[(size_t)(D + q) * H + tid], acc);
    ws[OFF_QP + br * H + tid] = acc;
    float p1 = qs[tid] * ws[OFF_U1 + tid];
    float p2 = qs[tid] * ws[OFF_U2 + tid];
    p1 = waveReduce(p1);
    p2 = waveReduce(p2);
    if (lane == 0) { red[wave] = p1; red[8 + wave] = p2; }
    __syncthreads();
    if (tid == 0) {
      float t1 = 0.f, t2 = 0.f;
#pragma unroll
      for (int i = 0; i < 8; ++i) { t1 += red[i]; t2 += red[8 + i]; }
      ws[OFF_QA1 + br] = t1;
      ws[OFF_QA2 + br] = t2;
      *qa1p = t1;
    }
    __syncthreads();
    float qa1 = *qa1p;
    const float4* vf = reinterpret_cast<const float4*>(ws + OFF_V1);
    float4 va = vf[lane];
    float4 vb = (lane < 11) ? vf[64 + lane] : make_float4(0.f, 0.f, 0.f, 0.f);
    for (int n = wave; n < N; n += 8) {
      const float4* rf = reinterpret_cast<const float4*>(orig + ((size_t)br * N + n) * D);
      float a0 = dot4(rf[lane], va);
      if (lane < 11) a0 += dot4(rf[64 + lane], vb);
      a0 = waveReduce(a0);
      if (lane == 0) ws[OFF_S1 + br * N + n] = a0 + qa1;
    }
    __syncthreads();
  }
  // scores2: grid-strided over all waves; 4 rows per group, 8 loads in flight.
  {
    const float4* vf = reinterpret_cast<const float4*>(ws + OFF_V2);
    float4 va = vf[lane];
    float4 vb = (lane < 11) ? vf[64 + lane] : make_float4(0.f, 0.f, 0.f, 0.f);
    for (int g = gw0; g < S / 4; g += gwN) {
      size_t r0 = (size_t)g * 4;
      const float4* P0 = reinterpret_cast<const float4*>(adj + (r0 + 0) * D);
      const float4* P1 = reinterpret_cast<const float4*>(adj + (r0 + 1) * D);
      const float4* P2 = reinterpret_cast<const float4*>(adj + (r0 + 2) * D);
      const float4* P3 = reinterpret_cast<const float4*>(adj + (r0 + 3) * D);
      float4 x0 = P0[lane], x1 = P1[lane], x2 = P2[lane], x3 = P3[lane];
      float a0 = dot4(x0, va), a1 = dot4(x1, va), a2 = dot4(x2, va), a3 = dot4(x3, va);
      if (lane < 11) {
        float4 y0 = P0[64 + lane], y1 = P1[64 + lane];
        float4 y2 = P2[64 + lane], y3 = P3[64 + lane];
        a0 += dot4(y0, vb); a1 += dot4(y1, vb);
        a2 += dot4(y2, vb); a3 += dot4(y3, vb);
      }
#pragma unroll
      for (int o = 32; o > 0; o >>= 1) {
        a0 += __shfl_xor(a0, o, 64);
        a1 += __shfl_xor(a1, o, 64);
        a2 += __shfl_xor(a2, o, 64);
        a3 += __shfl_xor(a3, o, 64);
      }
      float v = (lane == 0) ? a0 : (lane == 1) ? a1 : (lane == 2) ? a2 : a3;
      if (lane < 4) ws[OFF_RAW + r0 + lane] = v;
    }
  }
  grid.sync();

  // ---------- phase 2: softmax (jobs 0..31) + wo GEMM (jobs 32..351) ----------
  for (int vb = blockIdx.x; vb < 352; vb += nblk) {
    if (vb < 32) {
      int t = vb * 512 + tid;      // 0..16383 = B*N*E
      int b = t >> 12;
      int ne = t & 4095;
      int n = ne >> 6;
      const float* raw = ws + OFF_RAW;
      float v[R];
      float m = -1e30f;
#pragma unroll
      for (int r = 0; r < R; ++r) {
        int br = b * R + r;
        float sc = raw[(size_t)br * NE + ne] + ws[OFF_QA2 + br] + ws[OFF_S1 + br * N + n];
        sc = sc > 0.f ? sc : SLOPE * sc;
        v[r] = sc;
        m = fmaxf(m, sc);
      }
      float s = 0.f;
#pragma unroll
      for (int r = 0; r < R; ++r) { v[r] = __expf(v[r] - m); s += v[r]; }
      float inv = 1.f / s;
#pragma unroll
      for (int r = 0; r < R; ++r)
        ws[OFF_SC + (size_t)(b * R + r) * NE + ne] = v[r] * inv;
    } else {
      int bi = vb - 32;            // 0..319
      int br = bi >> 3, h0 = (bi & 7) * 64;
      float* sA = smem;            // 64x60
      float* sB = smem + 3840;     // 60x64
      const float4* sBf = reinterpret_cast<const float4*>(sB);
      int th = tid & 15, tn = tid >> 4;   // tn 0..31
      float ac[2][4] = {};
      for (int k0 = 0; k0 < D; k0 += 60) {
        __syncthreads();
        for (int idx = tid; idx < 3840; idx += 512) {
          int n = idx / 60, kk = idx % 60;
          sA[idx] = orig[((size_t)br * N + n) * D + k0 + kk];
        }
        for (int idx = tid; idx < 3840; idx += 512) {
          int kk = idx >> 6, hh = idx & 63;
          sB[idx] = W[(size_t)(k0 + kk) * H + h0 + hh];
        }
        __syncthreads();
#pragma unroll 4
        for (int kk = 0; kk < 60; ++kk) {
          float av0 = sA[(tn * 2 + 0) * 60 + kk];
          float av1 = sA[(tn * 2 + 1) * 60 + kk];
          float4 bv = sBf[kk * 16 + th];
          ac[0][0] = fmaf(av0, bv.x, ac[0][0]);
          ac[0][1] = fmaf(av0, bv.y, ac[0][1]);
          ac[0][2] = fmaf(av0, bv.z, ac[0][2]);
          ac[0][3] = fmaf(av0, bv.w, ac[0][3]);
          ac[1][0] = fmaf(av1, bv.x, ac[1][0]);
          ac[1][1] = fmaf(av1, bv.y, ac[1][1]);
          ac[1][2] = fmaf(av1, bv.z, ac[1][2]);
          ac[1][3] = fmaf(av1, bv.w, ac[1][3]);
        }
      }
#pragma unroll
      for (int i = 0; i < 2; ++i) {
        int n = tn * 2 + i;
#pragma unroll
        for (int j = 0; j < 4; ++j) {
          int h = h0 + th * 4 + j;
          ws[OFF_WO + ((size_t)br * N + n) * H + h] = ac[i][j] + ws[OFF_QP + br * H + h];
        }
      }
      __syncthreads();
    }
  }
  grid.sync();

  // ---------- phase 3: hprime = attn @ w_original, ELU ----------
  for (int vb = blockIdx.x; vb < 160; vb += nblk) {
    int br = vb >> 2, hc = vb & 3;
    int h = hc * 128 + (tid & 127);
    int ig = tid >> 7;               // 0..3 -> rows ig*16..ig*16+15
    float* sAtt = smem;              // 4096 floats
    __syncthreads();
    const float* att = ws + OFF_SC + (size_t)br * NE;
    for (int idx = tid; idx < 4096; idx += 512) sAtt[idx] = att[idx];
    __syncthreads();
    float acc[16] = {};
    const float* wo = ws + OFF_WO + (size_t)br * N * H;
    const float4* sAttf = reinterpret_cast<const float4*>(sAtt);
#pragma unroll 2
    for (int j4 = 0; j4 < 16; ++j4) {
      float w0 = wo[(size_t)(4 * j4 + 0) * H + h];
      float w1 = wo[(size_t)(4 * j4 + 1) * H + h];
      float w2 = wo[(size_t)(4 * j4 + 2) * H + h];
      float w3 = wo[(size_t)(4 * j4 + 3) * H + h];
#pragma unroll
      for (int ii = 0; ii < 16; ++ii) {
        float4 a4 = sAttf[(ig * 16 + ii) * 16 + j4];
        acc[ii] = fmaf(a4.x, w0, fmaf(a4.y, w1, fmaf(a4.z, w2, fmaf(a4.w, w3, acc[ii]))));
      }
    }
#pragma unroll
    for (int ii = 0; ii < 16; ++ii) {
      int i = ig * 16 + ii;
      float x = acc[ii];
      out[((size_t)br * N + i) * H + h] = x > 0.f ? x : expm1f(x);
    }
  }
}

extern "C" void kernel_launch(void* const* d_in, const int* in_sizes, int n_in,
                              void* d_out, int out_size, void* d_ws, size_t ws_size,
                              hipStream_t stream) {
  const float* adj  = (const float*)d_in[0];
  const float* orig = (const float*)d_in[1];
  const float* ques = (const float*)d_in[2];
  const float* W    = (const float*)d_in[3];
  const float* a    = (const float*)d_in[4];
  float* out = (float*)d_out;
  float* ws  = (float*)d_ws;

  int maxb = 0;
  (void)hipOccupancyMaxActiveBlocksPerMultiprocessor(&maxb, (const void*)k_mega, 512, 0);
  if (maxb < 1) maxb = 1;
  int grid = maxb * 256;
  if (grid > 1024) grid = 1024;

  void* args[] = {(void*)&adj, (void*)&orig, (void*)&ques, (void*)&W,
                  (void*)&a, (void*)&out, (void*)&ws};
  (void)hipLaunchCooperativeKernel((const void*)k_mega, dim3(grid), dim3(512),
                                   args, 0, stream);
}

// Round 15
// 136.421 us; speedup vs baseline: 2.1434x; 1.6841x over previous
//
#include <hip/hip_runtime.h>
#include <math.h>

namespace {
constexpr int B = 4, R = 10, N = 64, E = 64, D = 300, H = 512;
constexpr int BR = B * R;        // 40
constexpr int NE = N * E;        // 4096
constexpr int S = BR * NE;       // 163840
constexpr float SLOPE = 0.2f;

// ws layout (floats)
constexpr int OFF_V1  = 0;                 // 300   Wn @ a1
constexpr int OFF_V2  = OFF_V1 + 300;      // 300   Wn @ a2  (byte 1200, 16B-aligned)
constexpr int OFF_U1  = OFF_V2 + 300;      // 512   Wq @ a1
constexpr int OFF_U2  = OFF_U1 + H;        // 512   Wq @ a2
constexpr int OFF_QP  = OFF_U2 + H;        // 40*512 q_proj
constexpr int OFF_QA1 = OFF_QP + BR * H;   // 40
constexpr int OFF_QA2 = OFF_QA1 + BR;      // 40
constexpr int OFF_S1  = OFF_QA2 + BR;      // 2560  scores1[b,r,n] (incl. qa1)
constexpr int OFF_SC  = OFF_S1 + BR * N;   // 163840 attn (post-softmax)
constexpr int OFF_WO  = OFF_SC + S;        // 1310720 w_original
}

__device__ inline float waveReduce(float v) {
#pragma unroll
  for (int o = 32; o > 0; o >>= 1) v += __shfl_xor(v, o, 64);
  return v;
}

__device__ inline float dot4(float4 a, float4 b) {
  return a.x * b.x + a.y * b.y + a.z * b.z + a.w * b.w;
}

// grid 812 x 64: one wave per W row; dot with a1 and a2.
__global__ __launch_bounds__(64) void k_vecs(const float* __restrict__ W,
                                             const float* __restrict__ a,
                                             float* __restrict__ ws) {
  int row = blockIdx.x;
  int lane = threadIdx.x;
  const float4* rf  = reinterpret_cast<const float4*>(W + (size_t)row * H);
  const float4* a1f = reinterpret_cast<const float4*>(a);
  const float4* a2f = reinterpret_cast<const float4*>(a + H);
  float4 x0 = rf[lane], x1 = rf[64 + lane];
  float4 p0 = a1f[lane], p1 = a1f[64 + lane];
  float4 q0 = a2f[lane], q1 = a2f[64 + lane];
  float s1 = dot4(x0, p0) + dot4(x1, p1);
  float s2 = dot4(x0, q0) + dot4(x1, q1);
  s1 = waveReduce(s1);
  s2 = waveReduce(s2);
  if (lane == 0) {
    if (row < D) { ws[OFF_V1 + row] = s1; ws[OFF_V2 + row] = s2; }
    else         { ws[OFF_U1 + (row - D)] = s1; ws[OFF_U2 + (row - D)] = s2; }
  }
}

// grid 40 x 512: q_proj (4-way ILP accumulators) + qa1/qa2 + scores1 (2-row batch).
// R13 post-mortem: the old single-acc serial FMA chain (512 dep FMAs, each
// gated on a W load) made this ~20-25us with only 40 blocks resident.
__global__ __launch_bounds__(512) void k_qproj_s1(const float* __restrict__ ques,
                                                  const float* __restrict__ W,
                                                  const float* __restrict__ orig,
                                                  float* __restrict__ ws) {
  int br = blockIdx.x, h = threadIdx.x;
  __shared__ float qs[H];
  __shared__ float red[16];
  __shared__ float qa1s;
  qs[h] = ques[(size_t)br * H + h];
  __syncthreads();
  float ac0 = 0.f, ac1 = 0.f, ac2 = 0.f, ac3 = 0.f;
#pragma unroll 4
  for (int q = 0; q < H; q += 4) {
    ac0 = fmaf(qs[q + 0], W[(size_t)(D + q + 0) * H + h], ac0);
    ac1 = fmaf(qs[q + 1], W[(size_t)(D + q + 1) * H + h], ac1);
    ac2 = fmaf(qs[q + 2], W[(size_t)(D + q + 2) * H + h], ac2);
    ac3 = fmaf(qs[q + 3], W[(size_t)(D + q + 3) * H + h], ac3);
  }
  float acc = (ac0 + ac1) + (ac2 + ac3);
  ws[OFF_QP + br * H + h] = acc;
  float p1 = qs[h] * ws[OFF_U1 + h];
  float p2 = qs[h] * ws[OFF_U2 + h];
  p1 = waveReduce(p1);
  p2 = waveReduce(p2);
  int lane = h & 63, wave = h >> 6;
  if (lane == 0) { red[wave] = p1; red[8 + wave] = p2; }
  __syncthreads();
  if (h == 0) {
    float t1 = 0.f, t2 = 0.f;
#pragma unroll
    for (int i = 0; i < 8; ++i) { t1 += red[i]; t2 += red[8 + i]; }
    ws[OFF_QA1 + br] = t1;
    ws[OFF_QA2 + br] = t2;
    qa1s = t1;
  }
  __syncthreads();
  // scores1: rows wave*8..wave*8+7, batched 2 at a time for MLP.
  float qa1 = qa1s;
  const float4* vf = reinterpret_cast<const float4*>(ws + OFF_V1);
  float4 va = vf[lane];
  float4 vb = (lane < 11) ? vf[64 + lane] : make_float4(0.f, 0.f, 0.f, 0.f);
  for (int n2 = wave * 8; n2 < wave * 8 + 8; n2 += 2) {
    const float4* rf0 = reinterpret_cast<const float4*>(orig + ((size_t)br * N + n2) * D);
    const float4* rf1 = reinterpret_cast<const float4*>(orig + ((size_t)br * N + n2 + 1) * D);
    float a0 = dot4(rf0[lane], va);
    float a1 = dot4(rf1[lane], va);
    if (lane < 11) {
      a0 += dot4(rf0[64 + lane], vb);
      a1 += dot4(rf1[64 + lane], vb);
    }
#pragma unroll
    for (int o = 32; o > 0; o >>= 1) {
      a0 += __shfl_xor(a0, o, 64);
      a1 += __shfl_xor(a1, o, 64);
    }
    if (lane == 0) {
      ws[OFF_S1 + br * N + n2]     = a0 + qa1;
      ws[OFF_S1 + br * N + n2 + 1] = a1 + qa1;
    }
  }
}

// grid 4096 x 256: one wave per (b,n,e). Loads all R=10 adj rows for that
// triple (20 float4 loads in flight), 10 interleaved xor-reduces leave every
// lane holding all 10 r-scores -> leaky+softmax in-wave, attn written direct.
// Kills the RAW round-trip, the softmax kernel, and one boundary.
__global__ __launch_bounds__(256) void k_attn2(const float* __restrict__ adj,
                                               float* __restrict__ ws) {
  int wid = blockIdx.x * 4 + (threadIdx.x >> 6);   // 0..16383 = b*4096+ne
  int lane = threadIdx.x & 63;
  int b = wid >> 12, ne = wid & 4095, n = ne >> 6;
  const float4* vf = reinterpret_cast<const float4*>(ws + OFF_V2);
  float4 va = vf[lane];
  float4 vb = (lane < 11) ? vf[64 + lane] : make_float4(0.f, 0.f, 0.f, 0.f);
  const float* base = adj + ((size_t)b * R * N * E + ne) * D;   // + r*N*E*D
  float acc[R];
#pragma unroll
  for (int r = 0; r < R; ++r) {
    const float4* p = reinterpret_cast<const float4*>(base + (size_t)r * N * E * D);
    acc[r] = dot4(p[lane], va);
  }
  if (lane < 11) {
#pragma unroll
    for (int r = 0; r < R; ++r) {
      const float4* p = reinterpret_cast<const float4*>(base + (size_t)r * N * E * D);
      acc[r] += dot4(p[64 + lane], vb);
    }
  }
  int brb = b * R;
  float add[R];
#pragma unroll
  for (int r = 0; r < R; ++r)
    add[r] = ws[OFF_QA2 + brb + r] + ws[OFF_S1 + (brb + r) * N + n];
#pragma unroll
  for (int o = 32; o > 0; o >>= 1) {
#pragma unroll
    for (int r = 0; r < R; ++r) acc[r] += __shfl_xor(acc[r], o, 64);
  }
  float m = -1e30f;
#pragma unroll
  for (int r = 0; r < R; ++r) {
    float sc = acc[r] + add[r];
    sc = sc > 0.f ? sc : SLOPE * sc;
    acc[r] = sc;
    m = fmaxf(m, sc);
  }
  float s = 0.f;
#pragma unroll
  for (int r = 0; r < R; ++r) { acc[r] = __expf(acc[r] - m); s += acc[r]; }
  float inv = 1.f / s;
  if (lane == 0) {
#pragma unroll
    for (int r = 0; r < R; ++r)
      ws[OFF_SC + (size_t)(brb + r) * NE + ne] = acc[r] * inv;
  }
}

// grid (40, 8) x 256: w_original[br] = orig[br] @ Wn + q_proj[br]
__global__ __launch_bounds__(256) void k_wo(const float* __restrict__ orig,
                                            const float* __restrict__ W,
                                            float* __restrict__ ws) {
  int br = blockIdx.x, h0 = blockIdx.y * 64;
  int t = threadIdx.x;
  __shared__ __align__(16) float sA[64 * 60];
  __shared__ __align__(16) float sB[60 * 64];
  const float4* sBf = reinterpret_cast<const float4*>(sB);
  int tn = t >> 4, th = t & 15;
  float acc[4][4] = {};
  for (int k0 = 0; k0 < D; k0 += 60) {
    __syncthreads();
    for (int idx = t; idx < 64 * 60; idx += 256) {
      int n = idx / 60, kk = idx % 60;
      sA[idx] = orig[((size_t)br * N + n) * D + k0 + kk];
    }
    for (int idx = t; idx < 60 * 64; idx += 256) {
      int kk = idx >> 6, hh = idx & 63;
      sB[idx] = W[(size_t)(k0 + kk) * H + h0 + hh];
    }
    __syncthreads();
#pragma unroll 4
    for (int kk = 0; kk < 60; ++kk) {
      float av[4];
#pragma unroll
      for (int i = 0; i < 4; ++i) av[i] = sA[(tn * 4 + i) * 60 + kk];
      float4 bv = sBf[kk * 16 + th];
#pragma unroll
      for (int i = 0; i < 4; ++i) {
        acc[i][0] = fmaf(av[i], bv.x, acc[i][0]);
        acc[i][1] = fmaf(av[i], bv.y, acc[i][1]);
        acc[i][2] = fmaf(av[i], bv.z, acc[i][2]);
        acc[i][3] = fmaf(av[i], bv.w, acc[i][3]);
      }
    }
  }
#pragma unroll
  for (int i = 0; i < 4; ++i) {
    int n = tn * 4 + i;
#pragma unroll
    for (int j = 0; j < 4; ++j) {
      int h = h0 + th * 4 + j;
      ws[OFF_WO + ((size_t)br * N + n) * H + h] = acc[i][j] + ws[OFF_QP + br * H + h];
    }
  }
}

// grid (40, 4) x 256: h_prime[br] = attn[br] @ w_original[br], then ELU.
__global__ __launch_bounds__(256) void k_hprime(const float* __restrict__ ws,
                                                float* __restrict__ out) {
  int br = blockIdx.x;
  int h = blockIdx.y * 128 + (threadIdx.x & 127);
  int ig = threadIdx.x >> 7;
  __shared__ __align__(16) float sAtt[64 * 64];
  const float* att = ws + OFF_SC + (size_t)br * NE;
  for (int idx = threadIdx.x; idx < 4096; idx += 256) sAtt[idx] = att[idx];
  __syncthreads();
  float acc[32] = {};
  const float* wo = ws + OFF_WO + (size_t)br * N * H;
  const float4* sAttf = reinterpret_cast<const float4*>(sAtt);
#pragma unroll 2
  for (int j4 = 0; j4 < 16; ++j4) {
    float w0 = wo[(size_t)(4 * j4 + 0) * H + h];
    float w1 = wo[(size_t)(4 * j4 + 1) * H + h];
    float w2 = wo[(size_t)(4 * j4 + 2) * H + h];
    float w3 = wo[(size_t)(4 * j4 + 3) * H + h];
#pragma unroll
    for (int ii = 0; ii < 32; ++ii) {
      float4 a4 = sAttf[(ig * 32 + ii) * 16 + j4];
      acc[ii] = fmaf(a4.x, w0, fmaf(a4.y, w1, fmaf(a4.z, w2, fmaf(a4.w, w3, acc[ii]))));
    }
  }
#pragma unroll
  for (int ii = 0; ii < 32; ++ii) {
    int i = ig * 32 + ii;
    float x = acc[ii];
    out[((size_t)br * N + i) * H + h] = x > 0.f ? x : expm1f(x);
  }
}

extern "C" void kernel_launch(void* const* d_in, const int* in_sizes, int n_in,
                              void* d_out, int out_size, void* d_ws, size_t ws_size,
                              hipStream_t stream) {
  const float* adj  = (const float*)d_in[0];
  const float* orig = (const float*)d_in[1];
  const float* ques = (const float*)d_in[2];
  const float* W    = (const float*)d_in[3];
  const float* a    = (const float*)d_in[4];
  float* out = (float*)d_out;
  float* ws  = (float*)d_ws;

  k_vecs<<<dim3(D + H), dim3(64), 0, stream>>>(W, a, ws);
  k_qproj_s1<<<dim3(BR), dim3(512), 0, stream>>>(ques, W, orig, ws);
  k_attn2<<<dim3(B * NE / 4), dim3(256), 0, stream>>>(adj, ws);   // 4096 blocks
  k_wo<<<dim3(BR, 8), dim3(256), 0, stream>>>(orig, W, ws);
  k_hprime<<<dim3(BR, 4), dim3(256), 0, stream>>>(ws, out);
}

// Round 16
// 113.793 us; speedup vs baseline: 2.5696x; 1.1989x over previous
//
#include <hip/hip_runtime.h>
#include <math.h>

namespace {
constexpr int B = 4, R = 10, N = 64, E = 64, D = 300, H = 512;
constexpr int BR = B * R;        // 40
constexpr int NE = N * E;        // 4096
constexpr int S = BR * NE;       // 163840
constexpr float SLOPE = 0.2f;
constexpr int WO_BLOCKS = BR * 8;   // 320

// ws layout (floats)
constexpr int OFF_V1  = 0;                 // 300   Wn @ a1
constexpr int OFF_V2  = OFF_V1 + 300;      // 300   Wn @ a2  (byte 1200, 16B-aligned)
constexpr int OFF_U1  = OFF_V2 + 300;      // 512   Wq @ a1
constexpr int OFF_U2  = OFF_U1 + H;        // 512   Wq @ a2
constexpr int OFF_QP  = OFF_U2 + H;        // 40*512 q_proj
constexpr int OFF_QA1 = OFF_QP + BR * H;   // 40
constexpr int OFF_QA2 = OFF_QA1 + BR;      // 40
constexpr int OFF_S1  = OFF_QA2 + BR;      // 2560  scores1[b,r,n] (incl. qa1)
constexpr int OFF_SC  = OFF_S1 + BR * N;   // 163840 attn (post-softmax)
constexpr int OFF_WO  = OFF_SC + S;        // 1310720 w_original
}

__device__ inline float waveReduce(float v) {
#pragma unroll
  for (int o = 32; o > 0; o >>= 1) v += __shfl_xor(v, o, 64);
  return v;
}

__device__ inline float dot4(float4 a, float4 b) {
  return a.x * b.x + a.y * b.y + a.z * b.z + a.w * b.w;
}

// grid 812 x 64: one wave per W row; dot with a1 and a2.
__global__ __launch_bounds__(64) void k_vecs(const float* __restrict__ W,
                                             const float* __restrict__ a,
                                             float* __restrict__ ws) {
  int row = blockIdx.x;
  int lane = threadIdx.x;
  const float4* rf  = reinterpret_cast<const float4*>(W + (size_t)row * H);
  const float4* a1f = reinterpret_cast<const float4*>(a);
  const float4* a2f = reinterpret_cast<const float4*>(a + H);
  float4 x0 = rf[lane], x1 = rf[64 + lane];
  float4 p0 = a1f[lane], p1 = a1f[64 + lane];
  float4 q0 = a2f[lane], q1 = a2f[64 + lane];
  float s1 = dot4(x0, p0) + dot4(x1, p1);
  float s2 = dot4(x0, q0) + dot4(x1, q1);
  s1 = waveReduce(s1);
  s2 = waveReduce(s2);
  if (lane == 0) {
    if (row < D) { ws[OFF_V1 + row] = s1; ws[OFF_V2 + row] = s2; }
    else         { ws[OFF_U1 + (row - D)] = s1; ws[OFF_U2 + (row - D)] = s2; }
  }
}

// grid 40 x 512: q_proj (4-way ILP accumulators) + qa1/qa2 + scores1 (2-row batch).
__global__ __launch_bounds__(512) void k_qproj_s1(const float* __restrict__ ques,
                                                  const float* __restrict__ W,
                                                  const float* __restrict__ orig,
                                                  float* __restrict__ ws) {
  int br = blockIdx.x, h = threadIdx.x;
  __shared__ float qs[H];
  __shared__ float red[16];
  __shared__ float qa1s;
  qs[h] = ques[(size_t)br * H + h];
  __syncthreads();
  float ac0 = 0.f, ac1 = 0.f, ac2 = 0.f, ac3 = 0.f;
#pragma unroll 4
  for (int q = 0; q < H; q += 4) {
    ac0 = fmaf(qs[q + 0], W[(size_t)(D + q + 0) * H + h], ac0);
    ac1 = fmaf(qs[q + 1], W[(size_t)(D + q + 1) * H + h], ac1);
    ac2 = fmaf(qs[q + 2], W[(size_t)(D + q + 2) * H + h], ac2);
    ac3 = fmaf(qs[q + 3], W[(size_t)(D + q + 3) * H + h], ac3);
  }
  float acc = (ac0 + ac1) + (ac2 + ac3);
  ws[OFF_QP + br * H + h] = acc;
  float p1 = qs[h] * ws[OFF_U1 + h];
  float p2 = qs[h] * ws[OFF_U2 + h];
  p1 = waveReduce(p1);
  p2 = waveReduce(p2);
  int lane = h & 63, wave = h >> 6;
  if (lane == 0) { red[wave] = p1; red[8 + wave] = p2; }
  __syncthreads();
  if (h == 0) {
    float t1 = 0.f, t2 = 0.f;
#pragma unroll
    for (int i = 0; i < 8; ++i) { t1 += red[i]; t2 += red[8 + i]; }
    ws[OFF_QA1 + br] = t1;
    ws[OFF_QA2 + br] = t2;
    qa1s = t1;
  }
  __syncthreads();
  float qa1 = qa1s;
  const float4* vf = reinterpret_cast<const float4*>(ws + OFF_V1);
  float4 va = vf[lane];
  float4 vb = (lane < 11) ? vf[64 + lane] : make_float4(0.f, 0.f, 0.f, 0.f);
  for (int n2 = wave * 8; n2 < wave * 8 + 8; n2 += 2) {
    const float4* rf0 = reinterpret_cast<const float4*>(orig + ((size_t)br * N + n2) * D);
    const float4* rf1 = reinterpret_cast<const float4*>(orig + ((size_t)br * N + n2 + 1) * D);
    float a0 = dot4(rf0[lane], va);
    float a1 = dot4(rf1[lane], va);
    if (lane < 11) {
      a0 += dot4(rf0[64 + lane], vb);
      a1 += dot4(rf1[64 + lane], vb);
    }
#pragma unroll
    for (int o = 32; o > 0; o >>= 1) {
      a0 += __shfl_xor(a0, o, 64);
      a1 += __shfl_xor(a1, o, 64);
    }
    if (lane == 0) {
      ws[OFF_S1 + br * N + n2]     = a0 + qa1;
      ws[OFF_S1 + br * N + n2 + 1] = a1 + qa1;
    }
  }
}

// grid 4416 x 256, block-split:
//   blocks 0..319:  wo GEMM (br, h0) — independent of attn, runs first and
//                   overlaps its VALU work under the attn blocks' HBM waits.
//   blocks 320..4415: attn — one wave per (b,n,e): ALL 20 row-loads issued
//                   before any FMA (explicit register batch), interleaved
//                   reduces, in-wave softmax, direct attn store.
__global__ __launch_bounds__(256) void k_attn_wo(const float* __restrict__ adj,
                                                 const float* __restrict__ orig,
                                                 const float* __restrict__ W,
                                                 float* __restrict__ ws) {
  __shared__ __align__(16) float sA[64 * 60];
  __shared__ __align__(16) float sB[60 * 64];
  if (blockIdx.x < WO_BLOCKS) {
    // ---- w_original tile GEMM ----
    int bi = blockIdx.x;
    int br = bi >> 3, h0 = (bi & 7) * 64;
    int t = threadIdx.x;
    const float4* sBf = reinterpret_cast<const float4*>(sB);
    int tn = t >> 4, th = t & 15;
    float acc[4][4] = {};
    for (int k0 = 0; k0 < D; k0 += 60) {
      __syncthreads();
      for (int idx = t; idx < 64 * 60; idx += 256) {
        int n = idx / 60, kk = idx % 60;
        sA[idx] = orig[((size_t)br * N + n) * D + k0 + kk];
      }
      for (int idx = t; idx < 60 * 64; idx += 256) {
        int kk = idx >> 6, hh = idx & 63;
        sB[idx] = W[(size_t)(k0 + kk) * H + h0 + hh];
      }
      __syncthreads();
#pragma unroll 4
      for (int kk = 0; kk < 60; ++kk) {
        float av[4];
#pragma unroll
        for (int i = 0; i < 4; ++i) av[i] = sA[(tn * 4 + i) * 60 + kk];
        float4 bv = sBf[kk * 16 + th];
#pragma unroll
        for (int i = 0; i < 4; ++i) {
          acc[i][0] = fmaf(av[i], bv.x, acc[i][0]);
          acc[i][1] = fmaf(av[i], bv.y, acc[i][1]);
          acc[i][2] = fmaf(av[i], bv.z, acc[i][2]);
          acc[i][3] = fmaf(av[i], bv.w, acc[i][3]);
        }
      }
    }
#pragma unroll
    for (int i = 0; i < 4; ++i) {
      int n = tn * 4 + i;
#pragma unroll
      for (int j = 0; j < 4; ++j) {
        int h = h0 + th * 4 + j;
        ws[OFF_WO + ((size_t)br * N + n) * H + h] = acc[i][j] + ws[OFF_QP + br * H + h];
      }
    }
    return;
  }
  // ---- attn path ----
  int wid = (blockIdx.x - WO_BLOCKS) * 4 + (threadIdx.x >> 6);  // 0..16383
  int lane = threadIdx.x & 63;
  int b = wid >> 12, ne = wid & 4095, n = ne >> 6;
  const float4* vf = reinterpret_cast<const float4*>(ws + OFF_V2);
  float4 va = vf[lane];
  float4 vb = (lane < 11) ? vf[64 + lane] : make_float4(0.f, 0.f, 0.f, 0.f);
  const float* base = adj + ((size_t)b * R * N * E + ne) * D;   // + r*N*E*D
  float4 x[R], y[R];
#pragma unroll
  for (int r = 0; r < R; ++r)
    x[r] = reinterpret_cast<const float4*>(base + (size_t)r * N * E * D)[lane];
  if (lane < 11) {
#pragma unroll
    for (int r = 0; r < R; ++r)
      y[r] = reinterpret_cast<const float4*>(base + (size_t)r * N * E * D)[64 + lane];
  }
  int brb = b * R;
  float add[R];
#pragma unroll
  for (int r = 0; r < R; ++r)
    add[r] = ws[OFF_QA2 + brb + r] + ws[OFF_S1 + (brb + r) * N + n];
  float acc[R];
#pragma unroll
  for (int r = 0; r < R; ++r) acc[r] = dot4(x[r], va);
  if (lane < 11) {
#pragma unroll
    for (int r = 0; r < R; ++r) acc[r] += dot4(y[r], vb);
  }
#pragma unroll
  for (int o = 32; o > 0; o >>= 1) {
#pragma unroll
    for (int r = 0; r < R; ++r) acc[r] += __shfl_xor(acc[r], o, 64);
  }
  float m = -1e30f;
#pragma unroll
  for (int r = 0; r < R; ++r) {
    float sc = acc[r] + add[r];
    sc = sc > 0.f ? sc : SLOPE * sc;
    acc[r] = sc;
    m = fmaxf(m, sc);
  }
  float s = 0.f;
#pragma unroll
  for (int r = 0; r < R; ++r) { acc[r] = __expf(acc[r] - m); s += acc[r]; }
  float inv = 1.f / s;
  if (lane == 0) {
#pragma unroll
    for (int r = 0; r < R; ++r)
      ws[OFF_SC + (size_t)(brb + r) * NE + ne] = acc[r] * inv;
  }
}

// grid (40, 8) x 256: h_prime[br] = attn[br] @ w_original[br], then ELU.
// Widened from (40,4): 320 blocks -> better CU coverage.
__global__ __launch_bounds__(256) void k_hprime(const float* __restrict__ ws,
                                                float* __restrict__ out) {
  int br = blockIdx.x;
  int h = blockIdx.y * 64 + (threadIdx.x & 63);
  int ig = threadIdx.x >> 6;   // 0..3 -> rows ig*16..ig*16+15
  __shared__ __align__(16) float sAtt[64 * 64];
  const float* att = ws + OFF_SC + (size_t)br * NE;
  for (int idx = threadIdx.x; idx < 4096; idx += 256) sAtt[idx] = att[idx];
  __syncthreads();
  float acc[16] = {};
  const float* wo = ws + OFF_WO + (size_t)br * N * H;
  const float4* sAttf = reinterpret_cast<const float4*>(sAtt);
#pragma unroll 2
  for (int j4 = 0; j4 < 16; ++j4) {
    float w0 = wo[(size_t)(4 * j4 + 0) * H + h];
    float w1 = wo[(size_t)(4 * j4 + 1) * H + h];
    float w2 = wo[(size_t)(4 * j4 + 2) * H + h];
    float w3 = wo[(size_t)(4 * j4 + 3) * H + h];
#pragma unroll
    for (int ii = 0; ii < 16; ++ii) {
      float4 a4 = sAttf[(ig * 16 + ii) * 16 + j4];
      acc[ii] = fmaf(a4.x, w0, fmaf(a4.y, w1, fmaf(a4.z, w2, fmaf(a4.w, w3, acc[ii]))));
    }
  }
#pragma unroll
  for (int ii = 0; ii < 16; ++ii) {
    int i = ig * 16 + ii;
    float x = acc[ii];
    out[((size_t)br * N + i) * H + h] = x > 0.f ? x : expm1f(x);
  }
}

extern "C" void kernel_launch(void* const* d_in, const int* in_sizes, int n_in,
                              void* d_out, int out_size, void* d_ws, size_t ws_size,
                              hipStream_t stream) {
  const float* adj  = (const float*)d_in[0];
  const float* orig = (const float*)d_in[1];
  const float* ques = (const float*)d_in[2];
  const float* W    = (const float*)d_in[3];
  const float* a    = (const float*)d_in[4];
  float* out = (float*)d_out;
  float* ws  = (float*)d_ws;

  k_vecs<<<dim3(D + H), dim3(64), 0, stream>>>(W, a, ws);
  k_qproj_s1<<<dim3(BR), dim3(512), 0, stream>>>(ques, W, orig, ws);
  k_attn_wo<<<dim3(WO_BLOCKS + B * NE / 4), dim3(256), 0, stream>>>(adj, orig, W, ws);
  k_hprime<<<dim3(BR, 8), dim3(256), 0, stream>>>(ws, out);
}

// Round 17
// 104.612 us; speedup vs baseline: 2.7951x; 1.0878x over previous
//
#include <hip/hip_runtime.h>
#include <math.h>

namespace {
constexpr int B = 4, R = 10, N = 64, E = 64, D = 300, H = 512;
constexpr int BR = B * R;        // 40
constexpr int NE = N * E;        // 4096
constexpr int S = BR * NE;       // 163840
constexpr float SLOPE = 0.2f;
constexpr int WO_BLOCKS = BR * 8;     // 320
constexpr int ATTN_BLOCKS = 1024;     // 4096 waves, 4 units each (strided)
constexpr int ATTN_WAVES = ATTN_BLOCKS * 4;   // 4096
constexpr int UPW = (B * NE) / ATTN_WAVES;    // 4

// ws layout (floats)
constexpr int OFF_V1  = 0;                 // 300   Wn @ a1
constexpr int OFF_V2  = OFF_V1 + 300;      // 300   Wn @ a2  (byte 1200, 16B-aligned)
constexpr int OFF_U1  = OFF_V2 + 300;      // 512   Wq @ a1
constexpr int OFF_U2  = OFF_U1 + H;        // 512   Wq @ a2
constexpr int OFF_QP  = OFF_U2 + H;        // 40*512 q_proj
constexpr int OFF_QA1 = OFF_QP + BR * H;   // 40
constexpr int OFF_QA2 = OFF_QA1 + BR;      // 40
constexpr int OFF_S1  = OFF_QA2 + BR;      // 2560  scores1[b,r,n] (incl. qa1)
constexpr int OFF_SC  = OFF_S1 + BR * N;   // 163840 attn (post-softmax)
constexpr int OFF_WO  = OFF_SC + S;        // 1310720 w_original
}

__device__ inline float waveReduce(float v) {
#pragma unroll
  for (int o = 32; o > 0; o >>= 1) v += __shfl_xor(v, o, 64);
  return v;
}

__device__ inline float dot4(float4 a, float4 b) {
  return a.x * b.x + a.y * b.y + a.z * b.z + a.w * b.w;
}

// grid 812 x 64: one wave per W row; dot with a1 and a2.
__global__ __launch_bounds__(64) void k_vecs(const float* __restrict__ W,
                                             const float* __restrict__ a,
                                             float* __restrict__ ws) {
  int row = blockIdx.x;
  int lane = threadIdx.x;
  const float4* rf  = reinterpret_cast<const float4*>(W + (size_t)row * H);
  const float4* a1f = reinterpret_cast<const float4*>(a);
  const float4* a2f = reinterpret_cast<const float4*>(a + H);
  float4 x0 = rf[lane], x1 = rf[64 + lane];
  float4 p0 = a1f[lane], p1 = a1f[64 + lane];
  float4 q0 = a2f[lane], q1 = a2f[64 + lane];
  float s1 = dot4(x0, p0) + dot4(x1, p1);
  float s2 = dot4(x0, q0) + dot4(x1, q1);
  s1 = waveReduce(s1);
  s2 = waveReduce(s2);
  if (lane == 0) {
    if (row < D) { ws[OFF_V1 + row] = s1; ws[OFF_V2 + row] = s2; }
    else         { ws[OFF_U1 + (row - D)] = s1; ws[OFF_U2 + (row - D)] = s2; }
  }
}

// grid 40 x 512: q_proj (4-way ILP accumulators) + qa1/qa2 + scores1 (2-row batch).
__global__ __launch_bounds__(512) void k_qproj_s1(const float* __restrict__ ques,
                                                  const float* __restrict__ W,
                                                  const float* __restrict__ orig,
                                                  float* __restrict__ ws) {
  int br = blockIdx.x, h = threadIdx.x;
  __shared__ float qs[H];
  __shared__ float red[16];
  __shared__ float qa1s;
  qs[h] = ques[(size_t)br * H + h];
  __syncthreads();
  float ac0 = 0.f, ac1 = 0.f, ac2 = 0.f, ac3 = 0.f;
#pragma unroll 4
  for (int q = 0; q < H; q += 4) {
    ac0 = fmaf(qs[q + 0], W[(size_t)(D + q + 0) * H + h], ac0);
    ac1 = fmaf(qs[q + 1], W[(size_t)(D + q + 1) * H + h], ac1);
    ac2 = fmaf(qs[q + 2], W[(size_t)(D + q + 2) * H + h], ac2);
    ac3 = fmaf(qs[q + 3], W[(size_t)(D + q + 3) * H + h], ac3);
  }
  float acc = (ac0 + ac1) + (ac2 + ac3);
  ws[OFF_QP + br * H + h] = acc;
  float p1 = qs[h] * ws[OFF_U1 + h];
  float p2 = qs[h] * ws[OFF_U2 + h];
  p1 = waveReduce(p1);
  p2 = waveReduce(p2);
  int lane = h & 63, wave = h >> 6;
  if (lane == 0) { red[wave] = p1; red[8 + wave] = p2; }
  __syncthreads();
  if (h == 0) {
    float t1 = 0.f, t2 = 0.f;
#pragma unroll
    for (int i = 0; i < 8; ++i) { t1 += red[i]; t2 += red[8 + i]; }
    ws[OFF_QA1 + br] = t1;
    ws[OFF_QA2 + br] = t2;
    qa1s = t1;
  }
  __syncthreads();
  float qa1 = qa1s;
  const float4* vf = reinterpret_cast<const float4*>(ws + OFF_V1);
  float4 va = vf[lane];
  float4 vb = (lane < 11) ? vf[64 + lane] : make_float4(0.f, 0.f, 0.f, 0.f);
  for (int n2 = wave * 8; n2 < wave * 8 + 8; n2 += 2) {
    const float4* rf0 = reinterpret_cast<const float4*>(orig + ((size_t)br * N + n2) * D);
    const float4* rf1 = reinterpret_cast<const float4*>(orig + ((size_t)br * N + n2 + 1) * D);
    float a0 = dot4(rf0[lane], va);
    float a1 = dot4(rf1[lane], va);
    if (lane < 11) {
      a0 += dot4(rf0[64 + lane], vb);
      a1 += dot4(rf1[64 + lane], vb);
    }
#pragma unroll
    for (int o = 32; o > 0; o >>= 1) {
      a0 += __shfl_xor(a0, o, 64);
      a1 += __shfl_xor(a1, o, 64);
    }
    if (lane == 0) {
      ws[OFF_S1 + br * N + n2]     = a0 + qa1;
      ws[OFF_S1 + br * N + n2 + 1] = a1 + qa1;
    }
  }
}

__device__ __forceinline__ void attn_load_x(const float* __restrict__ adj, int u,
                                            int lane, float4 (&x)[R]) {
  const float* base = adj + ((size_t)(u >> 12) * R * NE + (u & 4095)) * D;
#pragma unroll
  for (int r = 0; r < R; ++r)
    x[r] = reinterpret_cast<const float4*>(base + (size_t)r * NE * D)[lane];
}

__device__ __forceinline__ void attn_compute(const float* __restrict__ adj,
                                             float* __restrict__ ws, int u, int lane,
                                             const float4 (&x)[R],
                                             float4 va, float4 vb) {
  int b = u >> 12, ne = u & 4095, n = ne >> 6, brb = b * R;
  const float* base = adj + ((size_t)b * R * NE + ne) * D;
  bool tl = lane < 11;
  // tail loads issued first; latency hides under dots + x-reduce.
  float4 y[R];
  if (tl) {
#pragma unroll
    for (int r = 0; r < R; ++r)
      y[r] = reinterpret_cast<const float4*>(base + (size_t)r * NE * D)[64 + lane];
  }
  float add[R];
#pragma unroll
  for (int r = 0; r < R; ++r)
    add[r] = ws[OFF_QA2 + brb + r] + ws[OFF_S1 + (brb + r) * N + n];
  float acc[R];
#pragma unroll
  for (int r = 0; r < R; ++r) acc[r] = dot4(x[r], va);
  if (tl) {
#pragma unroll
    for (int r = 0; r < R; ++r) acc[r] += dot4(y[r], vb);
  }
#pragma unroll
  for (int o = 32; o > 0; o >>= 1) {
#pragma unroll
    for (int r = 0; r < R; ++r) acc[r] += __shfl_xor(acc[r], o, 64);
  }
  float m = -1e30f;
#pragma unroll
  for (int r = 0; r < R; ++r) {
    float sc = acc[r] + add[r];
    sc = sc > 0.f ? sc : SLOPE * sc;
    acc[r] = sc;
    m = fmaxf(m, sc);
  }
  float s = 0.f;
#pragma unroll
  for (int r = 0; r < R; ++r) { acc[r] = __expf(acc[r] - m); s += acc[r]; }
  float inv = 1.f / s;
  if (lane == 0) {
#pragma unroll
    for (int r = 0; r < R; ++r)
      ws[OFF_SC + (size_t)(brb + r) * NE + ne] = acc[r] * inv;
  }
}

// grid 1344 x 256, block-split:
//   blocks 0..319:   wo GEMM (br, h0) — independent; overlaps attn's HBM waits.
//   blocks 320..1343: persistent attn — each wave owns 4 strided units with a
//                    depth-1 software pipeline: unit i+1's 10 row-loads are in
//                    flight while unit i computes (dots/reduce/softmax/store).
//                    Fixes the ~40% memory duty cycle of the unpipelined form.
__global__ __launch_bounds__(256) void k_attn_wo(const float* __restrict__ adj,
                                                 const float* __restrict__ orig,
                                                 const float* __restrict__ W,
                                                 float* __restrict__ ws) {
  __shared__ __align__(16) float sA[64 * 60];
  __shared__ __align__(16) float sB[60 * 64];
  if (blockIdx.x < WO_BLOCKS) {
    // ---- w_original tile GEMM ----
    int bi = blockIdx.x;
    int br = bi >> 3, h0 = (bi & 7) * 64;
    int t = threadIdx.x;
    const float4* sBf = reinterpret_cast<const float4*>(sB);
    int tn = t >> 4, th = t & 15;
    float acc[4][4] = {};
    for (int k0 = 0; k0 < D; k0 += 60) {
      __syncthreads();
      for (int idx = t; idx < 64 * 60; idx += 256) {
        int n = idx / 60, kk = idx % 60;
        sA[idx] = orig[((size_t)br * N + n) * D + k0 + kk];
      }
      for (int idx = t; idx < 60 * 64; idx += 256) {
        int kk = idx >> 6, hh = idx & 63;
        sB[idx] = W[(size_t)(k0 + kk) * H + h0 + hh];
      }
      __syncthreads();
#pragma unroll 4
      for (int kk = 0; kk < 60; ++kk) {
        float av[4];
#pragma unroll
        for (int i = 0; i < 4; ++i) av[i] = sA[(tn * 4 + i) * 60 + kk];
        float4 bv = sBf[kk * 16 + th];
#pragma unroll
        for (int i = 0; i < 4; ++i) {
          acc[i][0] = fmaf(av[i], bv.x, acc[i][0]);
          acc[i][1] = fmaf(av[i], bv.y, acc[i][1]);
          acc[i][2] = fmaf(av[i], bv.z, acc[i][2]);
          acc[i][3] = fmaf(av[i], bv.w, acc[i][3]);
        }
      }
    }
#pragma unroll
    for (int i = 0; i < 4; ++i) {
      int n = tn * 4 + i;
#pragma unroll
      for (int j = 0; j < 4; ++j) {
        int h = h0 + th * 4 + j;
        ws[OFF_WO + ((size_t)br * N + n) * H + h] = acc[i][j] + ws[OFF_QP + br * H + h];
      }
    }
    return;
  }
  // ---- persistent pipelined attn path ----
  int aw = (blockIdx.x - WO_BLOCKS) * 4 + (threadIdx.x >> 6);   // 0..4095
  int lane = threadIdx.x & 63;
  const float4* vf = reinterpret_cast<const float4*>(ws + OFF_V2);
  float4 va = vf[lane];
  float4 vb = (lane < 11) ? vf[64 + lane] : make_float4(0.f, 0.f, 0.f, 0.f);
  float4 xA[R], xB[R];
  attn_load_x(adj, aw, lane, xA);
#pragma unroll
  for (int i = 0; i < UPW; ++i) {
    int u = aw + i * ATTN_WAVES;
    if (i + 1 < UPW) {
      if (i & 1) attn_load_x(adj, aw + (i + 1) * ATTN_WAVES, lane, xA);
      else       attn_load_x(adj, aw + (i + 1) * ATTN_WAVES, lane, xB);
    }
    if (i & 1) attn_compute(adj, ws, u, lane, xB, va, vb);
    else       attn_compute(adj, ws, u, lane, xA, va, vb);
  }
}

// grid (40, 8) x 256: h_prime[br] = attn[br] @ w_original[br], then ELU.
__global__ __launch_bounds__(256) void k_hprime(const float* __restrict__ ws,
                                                float* __restrict__ out) {
  int br = blockIdx.x;
  int h = blockIdx.y * 64 + (threadIdx.x & 63);
  int ig = threadIdx.x >> 6;   // 0..3 -> rows ig*16..ig*16+15
  __shared__ __align__(16) float sAtt[64 * 64];
  const float* att = ws + OFF_SC + (size_t)br * NE;
  for (int idx = threadIdx.x; idx < 4096; idx += 256) sAtt[idx] = att[idx];
  __syncthreads();
  float acc[16] = {};
  const float* wo = ws + OFF_WO + (size_t)br * N * H;
  const float4* sAttf = reinterpret_cast<const float4*>(sAtt);
#pragma unroll 2
  for (int j4 = 0; j4 < 16; ++j4) {
    float w0 = wo[(size_t)(4 * j4 + 0) * H + h];
    float w1 = wo[(size_t)(4 * j4 + 1) * H + h];
    float w2 = wo[(size_t)(4 * j4 + 2) * H + h];
    float w3 = wo[(size_t)(4 * j4 + 3) * H + h];
#pragma unroll
    for (int ii = 0; ii < 16; ++ii) {
      float4 a4 = sAttf[(ig * 16 + ii) * 16 + j4];
      acc[ii] = fmaf(a4.x, w0, fmaf(a4.y, w1, fmaf(a4.z, w2, fmaf(a4.w, w3, acc[ii]))));
    }
  }
#pragma unroll
  for (int ii = 0; ii < 16; ++ii) {
    int i = ig * 16 + ii;
    float x = acc[ii];
    out[((size_t)br * N + i) * H + h] = x > 0.f ? x : expm1f(x);
  }
}

extern "C" void kernel_launch(void* const* d_in, const int* in_sizes, int n_in,
                              void* d_out, int out_size, void* d_ws, size_t ws_size,
                              hipStream_t stream) {
  const float* adj  = (const float*)d_in[0];
  const float* orig = (const float*)d_in[1];
  const float* ques = (const float*)d_in[2];
  const float* W    = (const float*)d_in[3];
  const float* a    = (const float*)d_in[4];
  float* out = (float*)d_out;
  float* ws  = (float*)d_ws;

  k_vecs<<<dim3(D + H), dim3(64), 0, stream>>>(W, a, ws);
  k_qproj_s1<<<dim3(BR), dim3(512), 0, stream>>>(ques, W, orig, ws);
  k_attn_wo<<<dim3(WO_BLOCKS + ATTN_BLOCKS), dim3(256), 0, stream>>>(adj, orig, W, ws);
  k_hprime<<<dim3(BR, 8), dim3(256), 0, stream>>>(ws, out);
}